// Round 2
// baseline (377.756 us; speedup 1.0000x reference)
//
#include <hip/hip_runtime.h>
#include <hip/hip_bf16.h>

// Problem constants: N=16, M=65536, FIN=32, FOUT=32, K=7
#define N_    16
#define M_    65536
#define FIN_  32
#define FOUT_ 32
#define K_    7

#define BLOCKS_   2048
#define THREADS_  256
#define WAVES_PB_ 4
#define NXCD_     8
#define NPAIR_    8        // 16 n values -> 8 pairs, one pair per XCD
#define ITERS_    4        // 4096 groups / 1024 waves-per-XCD

typedef __bf16 bf16x8 __attribute__((ext_vector_type(8)));
typedef float  f32x4  __attribute__((ext_vector_type(4)));

// ---------------------------------------------------------------------------
// Pass 1: fp32 -> bf16 convert into PAIR-INTERLEAVED layout:
//   xb2[p][m][j][f],  p = n>>1, j = n&1  (64 bf16 = 128 B per (p,m) = 1 line)
// So a gather for (m2, pair p) is exactly one fully-used 128 B cache line.
// x reads are nontemporal (dead after this); xb2 stores are REGULAR —
// we want xb2 resident in LLC for the gather kernel (round-1 lesson).
// ---------------------------------------------------------------------------
__global__ __launch_bounds__(256)
void convert_pair_kernel(const float* __restrict__ x, __bf16* __restrict__ xb2)
{
    const size_t tid = (size_t)blockIdx.x * blockDim.x + threadIdx.x; // 2,097,152
    const int f8 = (int)(tid & 3);
    const int m  = (int)((tid >> 2) & (M_ - 1));
    const int p  = (int)(tid >> 18);

    const float* s0 = x + ((size_t)(2 * p) * M_ + m) * FIN_ + f8 * 8;
    const float* s1 = s0 + (size_t)M_ * FIN_;   // n = 2p+1

    const f32x4 a0 = __builtin_nontemporal_load((const f32x4*)s0);
    const f32x4 a1 = __builtin_nontemporal_load((const f32x4*)s0 + 1);
    const f32x4 c0 = __builtin_nontemporal_load((const f32x4*)s1);
    const f32x4 c1 = __builtin_nontemporal_load((const f32x4*)s1 + 1);

    bf16x8 v0, v1;
    #pragma unroll
    for (int j = 0; j < 4; ++j) { v0[j] = (__bf16)a0[j]; v0[4 + j] = (__bf16)a1[j]; }
    #pragma unroll
    for (int j = 0; j < 4; ++j) { v1[j] = (__bf16)c0[j]; v1[4 + j] = (__bf16)c1[j]; }

    __bf16* d = xb2 + ((size_t)p * M_ + m) * 64 + f8 * 8;
    *(bf16x8*)(d)      = v0;   // j = 0 half of the line
    *(bf16x8*)(d + 32) = v1;   // j = 1 half of the line
}

// ---------------------------------------------------------------------------
// Pass 2: XCD-local paired gathers.
//   - blockIdx&7 pins a block to pair p; per-XCD gather working set = 8 MB.
//   - Each iteration computes BOTH n of the pair for one 16-m group: the two
//     64 B wave-gathers per (m,k) hit the same 128 B line (2nd is L1-hit).
//   - Software pipeline: idx/iv and gathers for iteration i+1 issued while
//     computing iteration i.
//   - B fragments in LDS (14 KB); out stores nontemporal (write-once).
// ---------------------------------------------------------------------------
__global__ __launch_bounds__(256, 4)
void gfc_pair_kernel(const __bf16* __restrict__ xb2,
                     const float* __restrict__ w,
                     const float* __restrict__ bias,
                     const int*   __restrict__ il,
                     const float* __restrict__ iv,
                     float* __restrict__ out)
{
    __shared__ __bf16 wlds[K_ * 2 * 64 * 8];   // [k][h][lane][8] = 14 KB

    const int lane = threadIdx.x & 63;
    const int col  = lane & 15;   // A-row (m offset in group) / C-col (o)
    const int kgrp = lane >> 4;   // 8-wide f-chunk

    // Stage B fragments once per block: frag[k][h][lane][j] = w[k][kg*8+j][h*16+c]
    for (int t = threadIdx.x; t < K_ * 2 * 64; t += THREADS_) {
        const int l  = t & 63;
        const int h  = (t >> 6) & 1;
        const int k  = t >> 7;
        const int c  = l & 15;
        const int kg = l >> 4;
        const float* wp = w + (size_t)k * (FIN_ * FOUT_)
                            + (size_t)(kg * 8) * FOUT_ + h * 16 + c;
        bf16x8 b;
        #pragma unroll
        for (int j = 0; j < 8; ++j) b[j] = (__bf16)wp[j * FOUT_];
        *(bf16x8*)(wlds + (size_t)t * 8) = b;
    }
    __syncthreads();

    const float b_lo = bias[col];
    const float b_hi = bias[16 + col];

    const int p    = blockIdx.x & (NXCD_ - 1);                          // pair / XCD
    const int widx = (blockIdx.x >> 3) * WAVES_PB_ + (threadIdx.x >> 6); // 0..1023
    const __bf16* xp = xb2 + (size_t)p * ((size_t)M_ * 64);             // 8 MB slice

    // ---- Pipeline prologue: idx/iv + gathers for it=0 ----
    int   idxs[K_];
    float ivs[K_];
    {
        const int m0 = (widx * ITERS_) * 16 + col;
        #pragma unroll
        for (int k = 0; k < K_; ++k) {
            idxs[k] = il[m0 * K_ + k];
            ivs[k]  = iv[m0 * K_ + k];
        }
    }
    bf16x8 raw0[K_], raw1[K_];
    #pragma unroll
    for (int k = 0; k < K_; ++k) {
        const __bf16* g = xp + (size_t)idxs[k] * 64 + kgrp * 8;
        raw0[k] = *(const bf16x8*)(g);        // j=0 half (n = 2p)
        raw1[k] = *(const bf16x8*)(g + 32);   // j=1 half (n = 2p+1), same line
    }

    for (int it = 0; it < ITERS_; ++it) {
        const bool has_next = (it + 1) < ITERS_;

        // 1) Next iteration's idx/iv loads.
        int   idxn[K_];
        float ivn[K_];
        if (has_next) {
            const int mn = (widx * ITERS_ + it + 1) * 16 + col;
            #pragma unroll
            for (int k = 0; k < K_; ++k) {
                idxn[k] = il[mn * K_ + k];
                ivn[k]  = iv[mn * K_ + k];
            }
        }

        // 2) Compute both n of the pair with gathers issued one iteration ago.
        f32x4 acc00 = {0.f, 0.f, 0.f, 0.f};   // n0, o[0:16)
        f32x4 acc01 = {0.f, 0.f, 0.f, 0.f};   // n0, o[16:32)
        f32x4 acc10 = {0.f, 0.f, 0.f, 0.f};   // n1, o[0:16)
        f32x4 acc11 = {0.f, 0.f, 0.f, 0.f};   // n1, o[16:32)
        #pragma unroll
        for (int k = 0; k < K_; ++k) {
            const float ivk = ivs[k];
            bf16x8 a0, a1;
            #pragma unroll
            for (int j = 0; j < 8; ++j) {
                a0[j] = (__bf16)((float)raw0[k][j] * ivk);
                a1[j] = (__bf16)((float)raw1[k][j] * ivk);
            }
            const bf16x8 bf0 = *(const bf16x8*)(wlds + ((k * 2 + 0) * 64 + lane) * 8);
            const bf16x8 bf1 = *(const bf16x8*)(wlds + ((k * 2 + 1) * 64 + lane) * 8);
            acc00 = __builtin_amdgcn_mfma_f32_16x16x32_bf16(a0, bf0, acc00, 0, 0, 0);
            acc01 = __builtin_amdgcn_mfma_f32_16x16x32_bf16(a0, bf1, acc01, 0, 0, 0);
            acc10 = __builtin_amdgcn_mfma_f32_16x16x32_bf16(a1, bf0, acc10, 0, 0, 0);
            acc11 = __builtin_amdgcn_mfma_f32_16x16x32_bf16(a1, bf1, acc11, 0, 0, 0);
        }

        // 3) raw consumed — issue next iteration's gathers.
        if (has_next) {
            #pragma unroll
            for (int k = 0; k < K_; ++k) {
                const __bf16* g = xp + (size_t)idxn[k] * 64 + kgrp * 8;
                raw0[k] = *(const bf16x8*)(g);
                raw1[k] = *(const bf16x8*)(g + 32);
            }
            #pragma unroll
            for (int k = 0; k < K_; ++k) { idxs[k] = idxn[k]; ivs[k] = ivn[k]; }
        }

        // 4) Epilogue: D row = m offset (kgrp*4+r), D col = o. 2 KB contiguous
        //    per n. Nontemporal: out is write-once.
        const int mb = (widx * ITERS_ + it) * 16;
        #pragma unroll
        for (int r = 0; r < 4; ++r) {
            const int mrow = mb + kgrp * 4 + r;
            float* op0 = out + ((size_t)(2 * p)     * M_ + mrow) * FOUT_;
            float* op1 = out + ((size_t)(2 * p + 1) * M_ + mrow) * FOUT_;
            __builtin_nontemporal_store(acc00[r] + b_lo, op0 + col);
            __builtin_nontemporal_store(acc01[r] + b_hi, op0 + 16 + col);
            __builtin_nontemporal_store(acc10[r] + b_lo, op1 + col);
            __builtin_nontemporal_store(acc11[r] + b_hi, op1 + 16 + col);
        }
    }
}

// ---------------------------------------------------------------------------
// Fallback (round-1 kernel) if ws_size is too small for the bf16 staging.
// ---------------------------------------------------------------------------
__global__ __launch_bounds__(256, 4)
void gfc_fallback_kernel(const float* __restrict__ x,
                         const float* __restrict__ w,
                         const float* __restrict__ bias,
                         const int*   __restrict__ index_list,
                         const float* __restrict__ index_value,
                         float* __restrict__ out)
{
    const int lane  = threadIdx.x & 63;
    const int col   = lane & 15;
    const int kgrp  = lane >> 4;

    const int waves_per_block = blockDim.x >> 6;
    const int wave_id     = blockIdx.x * waves_per_block + (threadIdx.x >> 6);
    const int total_waves = gridDim.x * waves_per_block;

    bf16x8 bfrag[K_][2];
    #pragma unroll
    for (int k = 0; k < K_; ++k) {
        #pragma unroll
        for (int h = 0; h < 2; ++h) {
            const float* wp = w + (size_t)k * (FIN_ * FOUT_)
                                + (size_t)(kgrp * 8) * FOUT_ + h * 16 + col;
            bf16x8 b;
            #pragma unroll
            for (int j = 0; j < 8; ++j)
                b[j] = (__bf16)wp[j * FOUT_];
            bfrag[k][h] = b;
        }
    }
    const float b_lo = bias[col];
    const float b_hi = bias[16 + col];

    for (int m = wave_id; m < M_; m += total_waves) {
        f32x4 acc0 = {0.f, 0.f, 0.f, 0.f};
        f32x4 acc1 = {0.f, 0.f, 0.f, 0.f};

        #pragma unroll
        for (int k = 0; k < K_; ++k) {
            const int   m2  = index_list[m * K_ + k];
            const float ivk = index_value[m * K_ + k];
            const float* ap = x + ((size_t)col * M_ + (size_t)m2) * FIN_ + kgrp * 8;
            const float4 v0 = *(const float4*)(ap);
            const float4 v1 = *(const float4*)(ap + 4);
            const float av[8] = {v0.x, v0.y, v0.z, v0.w, v1.x, v1.y, v1.z, v1.w};
            bf16x8 a;
            #pragma unroll
            for (int j = 0; j < 8; ++j)
                a[j] = (__bf16)(av[j] * ivk);
            acc0 = __builtin_amdgcn_mfma_f32_16x16x32_bf16(a, bfrag[k][0], acc0, 0, 0, 0);
            acc1 = __builtin_amdgcn_mfma_f32_16x16x32_bf16(a, bfrag[k][1], acc1, 0, 0, 0);
        }

        #pragma unroll
        for (int r = 0; r < 4; ++r) {
            const int n = kgrp * 4 + r;
            const size_t base = ((size_t)n * M_ + (size_t)m) * FOUT_;
            out[base + col]      = acc0[r] + b_lo;
            out[base + 16 + col] = acc1[r] + b_hi;
        }
    }
}

extern "C" void kernel_launch(void* const* d_in, const int* in_sizes, int n_in,
                              void* d_out, int out_size, void* d_ws, size_t ws_size,
                              hipStream_t stream) {
    const float* x    = (const float*)d_in[0];  // (N, M, FIN) fp32
    const float* w    = (const float*)d_in[1];  // (K, FIN, FOUT) fp32
    const float* bias = (const float*)d_in[2];  // (FOUT,) fp32
    const int*   il   = (const int*)  d_in[3];  // (M*K,) int32
    const float* iv   = (const float*)d_in[4];  // (M, K) fp32
    float* out = (float*)d_out;                 // (N, M, FOUT) fp32

    const size_t ws_needed = (size_t)M_ * N_ * FIN_ * sizeof(__bf16);  // 64 MB
    if (ws_size >= ws_needed) {
        __bf16* xb2 = (__bf16*)d_ws;
        const int t_total = NPAIR_ * M_ * 4;                 // 2,097,152 threads
        hipLaunchKernelGGL(convert_pair_kernel, dim3(t_total / 256), dim3(256), 0, stream,
                           x, xb2);
        hipLaunchKernelGGL(gfc_pair_kernel, dim3(BLOCKS_), dim3(THREADS_), 0, stream,
                           xb2, w, bias, il, iv, out);
    } else {
        hipLaunchKernelGGL(gfc_fallback_kernel, dim3(2048), dim3(256), 0, stream,
                           x, w, bias, il, iv, out);
    }
}